// Round 3
// baseline (648.707 us; speedup 1.0000x reference)
//
#include <hip/hip_runtime.h>
#include <cstdint>
#include <cstddef>

#define NNODES 50000
#define NEDGES 800000
#define NGR    64
#define INDIM  128
#define HIDD   64

typedef __attribute__((ext_vector_type(8))) _Float16 f16x8;
typedef __attribute__((ext_vector_type(2))) _Float16 half2v;
typedef __attribute__((ext_vector_type(4))) float f32x4;

__device__ __forceinline__ float lrelu(float x) { return x > 0.f ? x : 0.2f * x; }
__device__ __forceinline__ float eluf(float x)  { return x > 0.f ? x : expm1f(x); }
__device__ __forceinline__ unsigned short f2h(float x) {   // RNE via v_cvt_f16_f32
    _Float16 h = (_Float16)x;
    return __builtin_bit_cast(unsigned short, h);
}
__device__ __forceinline__ float h2f(unsigned short u) {
    return (float)__builtin_bit_cast(_Float16, u);
}
// fp16 lo/hi of a dword -> f32 (fpext form so fma-mix can fold)
__device__ __forceinline__ float h2lo(unsigned int u) {
    half2v h = __builtin_bit_cast(half2v, u);
    return (float)h.x;
}
__device__ __forceinline__ float h2hi(unsigned int u) {
    half2v h = __builtin_bit_cast(half2v, u);
    return (float)h.y;
}

// ---------------------------------------------------------------------------
// fp32 -> fp16 (weight matrices only)
// ---------------------------------------------------------------------------
__global__ void cvt_f2h(const float* __restrict__ in, unsigned short* __restrict__ out, int n4) {
    int i = blockIdx.x * 256 + threadIdx.x;
    if (i < n4) {
        float4 v = ((const float4*)in)[i];
        ushort4 o;
        o.x = f2h(v.x); o.y = f2h(v.y); o.z = f2h(v.z); o.w = f2h(v.w);
        ((ushort4*)out)[i] = o;
    }
}

// ---------------------------------------------------------------------------
// CSR build (both graphs batched via blockIdx.y). int64 inputs arrive int32.
// ---------------------------------------------------------------------------
__global__ void count_dst(const int* __restrict__ ei0, const int* __restrict__ ei1,
                          int* __restrict__ cnt, int E, int N) {
    const int* ei = blockIdx.y ? ei1 : ei0;
    int* c = cnt + blockIdx.y * N;
    int e = blockIdx.x * 256 + threadIdx.x;
    if (e < E) atomicAdd(&c[ei[E + e]], 1);
}

__global__ __launch_bounds__(256) void scan_part(const int* __restrict__ cnt,
                                                 int* __restrict__ psum, int n) {
    __shared__ int ws[4];
    const int* c = cnt + blockIdx.y * n;
    int* p = psum + blockIdx.y * 256;
    int lane = threadIdx.x & 63, w = threadIdx.x >> 6;
    int i = blockIdx.x * 256 + threadIdx.x;
    int v = (i < n) ? c[i] : 0;
    #pragma unroll
    for (int off = 32; off >= 1; off >>= 1) v += __shfl_xor(v, off, 64);
    if (lane == 0) ws[w] = v;
    __syncthreads();
    if (threadIdx.x == 0) p[blockIdx.x] = ws[0] + ws[1] + ws[2] + ws[3];
}

__global__ __launch_bounds__(256) void scan_tops(int* __restrict__ psum,
                                                 int* __restrict__ rp, int nb, int n) {
    __shared__ int wsum[4];
    int* p = psum + blockIdx.x * 256;
    int* r = rp + blockIdx.x * (n + 1);
    int tid = threadIdx.x, lane = tid & 63, w = tid >> 6;
    int v = (tid < nb) ? p[tid] : 0;
    int x = v;
    #pragma unroll
    for (int off = 1; off < 64; off <<= 1) {
        int t = __shfl_up(x, off, 64);
        if (lane >= off) x += t;
    }
    if (lane == 63) wsum[w] = x;
    __syncthreads();
    int add = 0;
    for (int k = 0; k < w; k++) add += wsum[k];
    int incl = x + add;
    if (tid < nb) p[tid] = incl - v;
    if (tid == nb - 1) r[n] = incl;
}

__global__ __launch_bounds__(256) void scan_fin(const int* __restrict__ cnt,
                                                const int* __restrict__ psum,
                                                int* __restrict__ rp, int n) {
    __shared__ int wsum[4];
    const int* c = cnt + blockIdx.y * n;
    const int* p = psum + blockIdx.y * 256;
    int* r = rp + blockIdx.y * (n + 1);
    int tid = threadIdx.x, lane = tid & 63, w = tid >> 6;
    int i = blockIdx.x * 256 + tid;
    int v = (i < n) ? c[i] : 0;
    int x = v;
    #pragma unroll
    for (int off = 1; off < 64; off <<= 1) {
        int t = __shfl_up(x, off, 64);
        if (lane >= off) x += t;
    }
    if (lane == 63) wsum[w] = x;
    __syncthreads();
    int add = p[blockIdx.x];
    for (int k = 0; k < w; k++) add += wsum[k];
    if (i < n) r[i] = x + add - v;
}

__global__ void fill_csr(const int* __restrict__ ei0, const int* __restrict__ ei1,
                         const int* __restrict__ rp, int* __restrict__ fc,
                         int* __restrict__ col, int E, int N) {
    int g = blockIdx.y;
    const int* ei = g ? ei1 : ei0;
    const int* r = rp + g * (N + 1);
    int* f = fc + g * N;
    int* cl = col + (size_t)g * E;
    int e = blockIdx.x * 256 + threadIdx.x;
    if (e < E) {
        int s = ei[e];
        int d = ei[E + e];
        int pos = atomicAdd(&f[d], 1);
        cl[r[d] + pos] = s;
    }
}

// ---------------------------------------------------------------------------
// MFMA fp16 GEMM with fused alpha epilogue.
// ---------------------------------------------------------------------------
template<int BN, int WM, int WN, bool AF32>
__global__ __launch_bounds__(256) void gemm_mfma(const void* __restrict__ A0,
                                                 const void* __restrict__ A1,
                                                 size_t Ags,
                                                 const unsigned short* __restrict__ Bw,
                                                 unsigned short* __restrict__ C,
                                                 size_t Cgs,
                                                 int M, int K, int N,
                                                 const float* __restrict__ a_src,
                                                 const float* __restrict__ a_dst,
                                                 float* __restrict__ as_o,
                                                 float* __restrict__ ad_o,
                                                 int hstride, int ags) {
    constexpr int BM = 128, BK = 64;
    constexpr int MI = WM / 16, NI = WN / 16;
    constexpr int LDA = BK + 8;
    __shared__ unsigned short Asm[BM * LDA];
    __shared__ unsigned short Bsm[BN * LDA];
    int gph = blockIdx.z;
    const float* Af = (const float*)(gph ? A1 : A0);
    const unsigned short* Ab = (const unsigned short*)A0 + (size_t)gph * Ags;
    unsigned short* Cg = C + (size_t)gph * Cgs;
    float* aso = as_o + (size_t)gph * ags;
    float* ado = ad_o + (size_t)gph * ags;
    int tid = threadIdx.x;
    int lane = tid & 63, wave = tid >> 6;
    int l15 = lane & 15, quad = lane >> 4;
    int wm0, wn0;
    if (BN == 128) { wm0 = (wave >> 1) * 64; wn0 = (wave & 1) * 64; }
    else           { wm0 = wave * 32;        wn0 = 0; }
    int row0 = blockIdx.x * BM;
    int c0 = blockIdx.y * BN;

    f32x4 acc[MI][NI];
    #pragma unroll
    for (int mi = 0; mi < MI; mi++)
        #pragma unroll
        for (int ni = 0; ni < NI; ni++)
            acc[mi][ni] = (f32x4){0.f, 0.f, 0.f, 0.f};

    for (int k0 = 0; k0 < K; k0 += BK) {
        #pragma unroll
        for (int q = 0; q < BM / 32; q++) {
            int idx = q * 256 + tid;
            int r = idx >> 3, kc = idx & 7;
            int row = row0 + r;
            if (AF32) {
                float4 v0 = make_float4(0.f, 0.f, 0.f, 0.f), v1 = v0;
                if (row < M) {
                    v0 = *(const float4*)(Af + (size_t)row * K + k0 + kc * 8);
                    v1 = *(const float4*)(Af + (size_t)row * K + k0 + kc * 8 + 4);
                }
                unsigned short t[8] = {f2h(v0.x), f2h(v0.y), f2h(v0.z), f2h(v0.w),
                                       f2h(v1.x), f2h(v1.y), f2h(v1.z), f2h(v1.w)};
                *(uint4*)&Asm[r * LDA + kc * 8] = *(uint4*)t;
            } else {
                uint4 v = make_uint4(0u, 0u, 0u, 0u);
                if (row < M) v = *(const uint4*)(Ab + (size_t)row * K + k0 + kc * 8);
                *(uint4*)&Asm[r * LDA + kc * 8] = v;
            }
        }
        #pragma unroll
        for (int q = 0; q < BN / 32; q++) {
            int idx = q * 256 + tid;
            int n  = idx & (BN - 1);
            int kc = idx / BN;
            unsigned short tmp[8];
            #pragma unroll
            for (int j = 0; j < 8; j++)
                tmp[j] = Bw[(size_t)(k0 + kc * 8 + j) * N + c0 + n];
            *(uint4*)&Bsm[n * LDA + kc * 8] = *(uint4*)tmp;
        }
        __syncthreads();
        #pragma unroll
        for (int kb = 0; kb < 2; kb++) {
            f16x8 af[MI], bfr[NI];
            #pragma unroll
            for (int mi = 0; mi < MI; mi++)
                af[mi] = *(f16x8*)&Asm[(wm0 + mi * 16 + l15) * LDA + kb * 32 + quad * 8];
            #pragma unroll
            for (int ni = 0; ni < NI; ni++)
                bfr[ni] = *(f16x8*)&Bsm[(wn0 + ni * 16 + l15) * LDA + kb * 32 + quad * 8];
            #pragma unroll
            for (int mi = 0; mi < MI; mi++)
                #pragma unroll
                for (int ni = 0; ni < NI; ni++)
                    acc[mi][ni] = __builtin_amdgcn_mfma_f32_16x16x32_f16(
                        af[mi], bfr[ni], acc[mi][ni], 0, 0, 0);
        }
        __syncthreads();
    }
    #pragma unroll
    for (int mi = 0; mi < MI; mi++) {
        #pragma unroll
        for (int r = 0; r < 4; r++) {
            int row = row0 + wm0 + mi * 16 + quad * 4 + r;
            if (row < M) {
                #pragma unroll
                for (int ni = 0; ni < NI; ni++) {
                    int colg = c0 + wn0 + ni * 16 + l15;
                    Cg[(size_t)row * N + colg] = f2h(acc[mi][ni][r]);
                }
            }
        }
    }
    int headc = (c0 + wn0) >> 6;
    float a_s[NI], a_d[NI];
    #pragma unroll
    for (int ni = 0; ni < NI; ni++) {
        a_s[ni] = a_src[headc * 64 + ni * 16 + l15];
        a_d[ni] = a_dst[headc * 64 + ni * 16 + l15];
    }
    #pragma unroll
    for (int mi = 0; mi < MI; mi++) {
        #pragma unroll
        for (int r = 0; r < 4; r++) {
            float ps = 0.f, pd = 0.f;
            #pragma unroll
            for (int ni = 0; ni < NI; ni++) {
                ps += acc[mi][ni][r] * a_s[ni];
                pd += acc[mi][ni][r] * a_d[ni];
            }
            #pragma unroll
            for (int off = 1; off < 16; off <<= 1) {
                ps += __shfl_xor(ps, off, 64);
                pd += __shfl_xor(pd, off, 64);
            }
            int row = row0 + wm0 + mi * 16 + quad * 4 + r;
            if (l15 == 0 && row < M) {
                aso[row * hstride + headc] = ps;
                ado[row * hstride + headc] = pd;
            }
        }
    }
}

// ---------------------------------------------------------------------------
// wprep4: per-node softmax weight precompute, 4 heads. One wave per node.
// lane = h*16 + i. Pass 1: denominator. Pass 2: write NORMALIZED alpha (fp16,
// CSR edge order, [e*4+h]). Self-loop alpha0 (fp32, [node*4+h]).
// as/ad tables are ~800KB -> L2 resident; gathers are cheap here and are
// REMOVED from the hot aggregation loop entirely.
// ---------------------------------------------------------------------------
__global__ __launch_bounds__(256) void wprep4(const float* __restrict__ as_,
                                              const float* __restrict__ ad_,
                                              const int* __restrict__ rp,
                                              const int* __restrict__ col,
                                              unsigned short* __restrict__ alpha,
                                              float* __restrict__ alpha0,
                                              int n, int E) {
    int gph = blockIdx.y;
    const float* as = as_ + (size_t)gph * n * 4;
    const float* ad = ad_ + (size_t)gph * n * 4;
    const int* r = rp + gph * (n + 1);
    const int* cl = col + (size_t)gph * E;
    unsigned short* al = alpha + (size_t)gph * E * 4;
    float* al0 = alpha0 + (size_t)gph * n * 4;

    int wave = threadIdx.x >> 6, lane = threadIdx.x & 63;
    int node = blockIdx.x * 4 + wave;
    if (node >= n) return;
    int h = lane >> 4, i = lane & 15;
    float adn = ad[node * 4 + h];
    float asn = as[node * 4 + h];
    float w0 = __expf(lrelu(asn + adn));
    int beg = __builtin_amdgcn_readfirstlane(r[node]);
    int end = __builtin_amdgcn_readfirstlane(r[node + 1]);
    float den = 0.f;
    for (int j = beg; j < end; j += 16) {
        int idx = j + i;
        bool v = idx < end;
        int ix = v ? idx : beg;
        int colv = cl[ix];
        float w = __expf(lrelu(as[colv * 4 + h] + adn));
        den += v ? w : 0.f;
    }
    #pragma unroll
    for (int off = 1; off < 16; off <<= 1) den += __shfl_xor(den, off, 64);
    den += w0;
    float rden = 1.f / (den + 1e-16f);
    for (int j = beg; j < end; j += 16) {
        int idx = j + i;
        bool v = idx < end;
        int ix = v ? idx : beg;
        int colv = cl[ix];
        float w = __expf(lrelu(as[colv * 4 + h] + adn));
        if (v) al[(size_t)idx * 4 + h] = f2h(w * rden);
    }
    if (i == 0) al0[node * 4 + h] = w0 * rden;
}

// H=1 variant for conv2.
__global__ __launch_bounds__(256) void wprep1(const float* __restrict__ as_,
                                              const float* __restrict__ ad_,
                                              const int* __restrict__ rp,
                                              const int* __restrict__ col,
                                              unsigned short* __restrict__ alpha,
                                              float* __restrict__ alpha0,
                                              int n, int E) {
    int gph = blockIdx.y;
    const float* as = as_ + (size_t)gph * n;
    const float* ad = ad_ + (size_t)gph * n;
    const int* r = rp + gph * (n + 1);
    const int* cl = col + (size_t)gph * E;
    unsigned short* al = alpha + (size_t)gph * E;
    float* al0 = alpha0 + (size_t)gph * n;

    int wave = threadIdx.x >> 6, lane = threadIdx.x & 63;
    int node = blockIdx.x * 4 + wave;
    if (node >= n) return;
    float adn = ad[node];
    float w0 = __expf(lrelu(as[node] + adn));
    int beg = __builtin_amdgcn_readfirstlane(r[node]);
    int end = __builtin_amdgcn_readfirstlane(r[node + 1]);
    float den = 0.f;
    for (int j = beg; j < end; j += 64) {
        int idx = j + lane;
        bool v = idx < end;
        int ix = v ? idx : beg;
        int colv = cl[ix];
        float w = __expf(lrelu(as[colv] + adn));
        den += v ? w : 0.f;
    }
    #pragma unroll
    for (int off = 1; off < 64; off <<= 1) den += __shfl_xor(den, off, 64);
    den += w0;
    float rden = 1.f / (den + 1e-16f);
    for (int j = beg; j < end; j += 64) {
        int idx = j + lane;
        bool v = idx < end;
        int ix = v ? idx : beg;
        int colv = cl[ix];
        float w = __expf(lrelu(as[colv] + adn));
        if (v) al[idx] = f2h(w * rden);
    }
    if (lane == 0) al0[node] = w0 * rden;
}

// ---------------------------------------------------------------------------
// agg4_seq: conv1 aggregation with precomputed normalized alpha.
// One wave per dst node; lane owns channels [4*lane, 4*lane+4) (ushort4 = 8B,
// the wave's 64 lanes cover the full 512B row in ONE load). Edges serial,
// 8-deep unrolled: col/bounds are wave-uniform (s_load), alpha is a 16B-span
// broadcast load, 8 independent row loads in flight. No shfl, no reduction.
// ---------------------------------------------------------------------------
__global__ __launch_bounds__(256) void agg4_seq(const unsigned short* __restrict__ h,
                                                size_t hgs,
                                                const unsigned short* __restrict__ alpha,
                                                const float* __restrict__ alpha0,
                                                const int* __restrict__ rp,
                                                const int* __restrict__ col,
                                                const float* __restrict__ bias,
                                                unsigned short* __restrict__ out,
                                                size_t ogs, int n, int E) {
    int gph = blockIdx.y;
    const unsigned short* hg = h + (size_t)gph * hgs;
    const unsigned short* al = alpha + (size_t)gph * E * 4;
    const float* al0 = alpha0 + (size_t)gph * n * 4;
    const int* r = rp + gph * (n + 1);
    const int* cl = col + (size_t)gph * E;
    unsigned short* og = out + (size_t)gph * ogs;

    int wave = threadIdx.x >> 6, c = threadIdx.x & 63;
    int node = blockIdx.x * 4 + wave;
    if (node >= n) return;
    int head = c >> 4;                       // channels [4c,4c+4) -> head 4c/64

    // self loop (alpha0 pre-normalized)
    float a0w = al0[node * 4 + head];
    uint2 hu = *(const uint2*)(hg + (size_t)node * 256 + c * 4);
    float a[4];
    a[0] = h2lo(hu.x) * a0w; a[1] = h2hi(hu.x) * a0w;
    a[2] = h2lo(hu.y) * a0w; a[3] = h2hi(hu.y) * a0w;

    int beg = __builtin_amdgcn_readfirstlane(r[node]);
    int end = __builtin_amdgcn_readfirstlane(r[node + 1]);
    for (int j = beg; j < end; j += 8) {
        float we[8]; uint2 uu[8];
        #pragma unroll
        for (int k = 0; k < 8; k++) {
            int idx = j + k;
            bool v = idx < end;
            int ix = v ? idx : beg;
            int s = cl[ix];                                   // uniform -> SGPR
            unsigned short aw = al[(size_t)ix * 4 + head];    // 16B-span bcast
            we[k] = v ? h2f(aw) : 0.f;
            uu[k] = *(const uint2*)(hg + (size_t)s * 256 + c * 4);
        }
        #pragma unroll
        for (int k = 0; k < 8; k++) {
            a[0] = fmaf(h2lo(uu[k].x), we[k], a[0]);
            a[1] = fmaf(h2hi(uu[k].x), we[k], a[1]);
            a[2] = fmaf(h2lo(uu[k].y), we[k], a[2]);
            a[3] = fmaf(h2hi(uu[k].y), we[k], a[3]);
        }
    }
    float4 bq = ((const float4*)bias)[c];
    ushort4 t;
    t.x = f2h(eluf(a[0] + bq.x));
    t.y = f2h(eluf(a[1] + bq.y));
    t.z = f2h(eluf(a[2] + bq.z));
    t.w = f2h(eluf(a[3] + bq.w));
    *(uint2*)(og + (size_t)node * 256 + c * 4) = *(uint2*)&t;
}

// ---------------------------------------------------------------------------
// agg1_seq: conv2 aggregation, precomputed alpha. Two nodes per wave:
// p = lane>>5 selects node, c = lane&31 owns channels [2c,2c+2) (dword).
// Per-lane serial edge loop (halves may diverge; exec mask handles it).
// Output g2 in fp32.
// ---------------------------------------------------------------------------
__global__ __launch_bounds__(256) void agg1_seq(const unsigned short* __restrict__ h,
                                                size_t hgs,
                                                const unsigned short* __restrict__ alpha,
                                                const float* __restrict__ alpha0,
                                                const int* __restrict__ rp,
                                                const int* __restrict__ col,
                                                const float* __restrict__ bias,
                                                float* __restrict__ out,
                                                size_t ogs, int n, int E) {
    int gph = blockIdx.y;
    const unsigned short* hg = h + (size_t)gph * hgs;
    const unsigned short* al = alpha + (size_t)gph * E;
    const float* al0 = alpha0 + (size_t)gph * n;
    const int* r = rp + gph * (n + 1);
    const int* cl = col + (size_t)gph * E;
    float* og = out + (size_t)gph * ogs;

    int wave = threadIdx.x >> 6, lane = threadIdx.x & 63;
    int p = lane >> 5, c = lane & 31;
    int node = blockIdx.x * 8 + wave * 2 + p;
    if (node >= n) return;

    float a0w = al0[node];
    unsigned int hu = *(const unsigned int*)(hg + (size_t)node * 64 + c * 2);
    float a0 = h2lo(hu) * a0w, a1 = h2hi(hu) * a0w;

    int beg = r[node], end = r[node + 1];
    for (int j = beg; j < end; j += 8) {
        float we[8]; unsigned int uu[8];
        #pragma unroll
        for (int k = 0; k < 8; k++) {
            int idx = j + k;
            bool v = idx < end;
            int ix = v ? idx : beg;
            int s = cl[ix];
            unsigned short aw = al[ix];
            we[k] = v ? h2f(aw) : 0.f;
            uu[k] = *(const unsigned int*)(hg + (size_t)s * 64 + c * 2);
        }
        #pragma unroll
        for (int k = 0; k < 8; k++) {
            a0 = fmaf(h2lo(uu[k]), we[k], a0);
            a1 = fmaf(h2hi(uu[k]), we[k], a1);
        }
    }
    float2 bq = ((const float2*)bias)[c];
    float2 o;
    o.x = eluf(a0 + bq.x);
    o.y = eluf(a1 + bq.y);
    *(float2*)(og + (size_t)node * 64 + c * 2) = o;
}

// ---------------------------------------------------------------------------
// Mean pool over SORTED batch ids
// ---------------------------------------------------------------------------
__device__ __forceinline__ int lbound(const int* __restrict__ a, int n, int key) {
    int lo = 0, hi = n;
    while (lo < hi) {
        int mid = (lo + hi) >> 1;
        if (a[mid] < key) lo = mid + 1; else hi = mid;
    }
    return lo;
}

__global__ __launch_bounds__(256) void pool_mean(const float* __restrict__ g2,
                                                 size_t ggs,
                                                 const int* __restrict__ b0,
                                                 const int* __restrict__ b1,
                                                 float* __restrict__ out, int n) {
    __shared__ float red[4][64];
    __shared__ int bnds[2];
    int gph = blockIdx.y;
    const int* batch = gph ? b1 : b0;
    const float* gg = g2 + (size_t)gph * ggs;
    float* og = out + (size_t)gph * NGR * HIDD;
    int g = blockIdx.x;
    if (threadIdx.x < 2) bnds[threadIdx.x] = lbound(batch, n, g + (int)threadIdx.x);
    __syncthreads();
    int s = bnds[0], e = bnds[1];
    int lane = threadIdx.x & 63, wave = threadIdx.x >> 6;
    float acc = 0.f;
    for (int i = s + wave; i < e; i += 4)
        acc += gg[(size_t)i * 64 + lane];
    red[wave][lane] = acc;
    __syncthreads();
    if (wave == 0) {
        float sum = red[0][lane] + red[1][lane] + red[2][lane] + red[3][lane];
        og[g * 64 + lane] = sum / fmaxf((float)(e - s), 1.0f);
    }
}

// ---------------------------------------------------------------------------
extern "C" void kernel_launch(void* const* d_in, const int* in_sizes, int n_in,
                              void* d_out, int out_size, void* d_ws, size_t ws_size,
                              hipStream_t stream) {
    const int N = NNODES, E = NEDGES;

    const float* x1 = (const float*)d_in[0];
    const float* x2 = (const float*)d_in[3];
    const int* ei1v = (const int*)d_in[1];
    const int* ei2v = (const int*)d_in[4];
    const int* ba1  = (const int*)d_in[2];
    const int* ba2  = (const int*)d_in[5];
    const float* W1     = (const float*)d_in[6];
    const float* a_src1 = (const float*)d_in[7];
    const float* a_dst1 = (const float*)d_in[8];
    const float* b1     = (const float*)d_in[9];
    const float* W2     = (const float*)d_in[10];
    const float* a_src2 = (const float*)d_in[11];
    const float* a_dst2 = (const float*)d_in[12];
    const float* b2     = (const float*)d_in[13];

    // Workspace (~131 MB):
    //  R1: h1 fp16 (51.2M) -> g2 fp32 (25.6M after h1 dead)
    //  R2: g1 fp16 (51.2M)
    //  R3: alpha1 fp16 (12.8M) -> h2 fp16 (12.8M after agg4_seq)
    char* ws = (char*)d_ws;
    size_t off = 0;
    auto carve = [&](size_t bytes) -> char* {
        char* p = ws + off;
        off = (off + bytes + 255) & ~(size_t)255;
        return p;
    };
    char* R1 = carve((size_t)2 * N * 256 * 2);
    char* R2 = carve((size_t)2 * N * 256 * 2);
    char* R3 = carve((size_t)2 * E * 4 * 2);          // == 2*N*64*2 bytes
    int*   col  = (int*)carve((size_t)2 * E * 4);
    int*   rp   = (int*)carve((size_t)2 * (N + 1) * 4);
    int*   cntN = (int*)carve((size_t)2 * N * 4);
    int*   psum = (int*)carve(2 * 256 * 4);
    float* as1  = (float*)carve((size_t)2 * N * 4 * 4);
    float* ad1  = (float*)carve((size_t)2 * N * 4 * 4);
    float* as2  = (float*)carve((size_t)2 * N * 4);
    float* ad2  = (float*)carve((size_t)2 * N * 4);
    float* al01 = (float*)carve((size_t)2 * N * 4 * 4);
    float* al02 = (float*)carve((size_t)2 * N * 4);
    unsigned short* alpha2 = (unsigned short*)carve((size_t)2 * E * 2);
    unsigned short* W1h = (unsigned short*)carve(INDIM * 256 * 2);
    unsigned short* W2h = (unsigned short*)carve(256 * HIDD * 2);

    unsigned short* h1 = (unsigned short*)R1;            // [2][N*256] fp16
    unsigned short* g1 = (unsigned short*)R2;            // [2][N*256] fp16
    unsigned short* alpha1 = (unsigned short*)R3;        // [2][E*4] fp16
    unsigned short* h2 = (unsigned short*)R3;            // [2][N*64] fp16 (after agg4)
    float* g2 = (float*)R1;                              // [2][N*64] fp32 (after h1 dead)

    float* outF = (float*)d_out;

    const int nodeBlocks = (N + 3) / 4;
    const int nb = (N + 255) / 256;
    const int eb = (E + 255) / 256;

    // weight conversions (tiny)
    cvt_f2h<<<(INDIM * 256 / 4 + 255) / 256, 256, 0, stream>>>(W1, W1h, INDIM * 256 / 4);
    cvt_f2h<<<(256 * HIDD / 4 + 255) / 256, 256, 0, stream>>>(W2, W2h, 256 * HIDD / 4);

    // CSR build
    hipMemsetAsync(cntN, 0, (size_t)2 * N * 4, stream);
    count_dst<<<dim3(eb, 2), 256, 0, stream>>>(ei1v, ei2v, cntN, E, N);
    scan_part<<<dim3(nb, 2), 256, 0, stream>>>(cntN, psum, N);
    scan_tops<<<2, 256, 0, stream>>>(psum, rp, nb, N);
    scan_fin<<<dim3(nb, 2), 256, 0, stream>>>(cntN, psum, rp, N);
    hipMemsetAsync(cntN, 0, (size_t)2 * N * 4, stream);
    fill_csr<<<dim3(eb, 2), 256, 0, stream>>>(ei1v, ei2v, rp, cntN, col, E, N);

    // conv1: h1 = x @ W1 (fp32 A staged in-kernel), alpha logits fused
    gemm_mfma<128, 64, 64, true><<<dim3(391, 2, 2), 256, 0, stream>>>(
        x1, x2, 0, W1h, h1, (size_t)N * 256, N, INDIM, 256,
        a_src1, a_dst1, as1, ad1, 4, N * 4);
    wprep4<<<dim3(nodeBlocks, 2), 256, 0, stream>>>(as1, ad1, rp, col, alpha1, al01, N, E);
    agg4_seq<<<dim3(nodeBlocks, 2), 256, 0, stream>>>(h1, (size_t)N * 256, alpha1, al01,
                                                      rp, col, b1, g1, (size_t)N * 256, N, E);

    // conv2: h2 = g1 @ W2 (fp16 A), alpha logits fused (h2 overwrites alpha1)
    gemm_mfma<64, 32, 64, false><<<dim3(391, 1, 2), 256, 0, stream>>>(
        g1, nullptr, (size_t)N * 256, W2h, h2, (size_t)N * 64, N, 256, HIDD,
        a_src2, a_dst2, as2, ad2, 1, N);
    wprep1<<<dim3(nodeBlocks, 2), 256, 0, stream>>>(as2, ad2, rp, col, alpha2, al02, N, E);
    agg1_seq<<<dim3((N + 7) / 8, 2), 256, 0, stream>>>(h2, (size_t)N * 64, alpha2, al02,
                                                       rp, col, b2, g2, (size_t)N * 64, N, E);

    // mean pool
    pool_mean<<<dim3(NGR, 2), 256, 0, stream>>>(g2, (size_t)N * 64, ba1, ba2, outF, N);
}